// Round 1
// baseline (1983.727 us; speedup 1.0000x reference)
//
#include <hip/hip_runtime.h>
#include <math.h>

#define D 64

// C[M,64] = A[M,64] @ W[64,64]; MODE 1: C = tanh(C * gate)
template <int MODE>
__global__ __launch_bounds__(256) void gemm64(const float* __restrict__ A,
                                              const float* __restrict__ W,
                                              const float* __restrict__ gate,
                                              float* __restrict__ C, int M) {
    __shared__ float At[64 * 68];   // A-tile transposed: At[k][r], stride 68 (pad)
    __shared__ float Wl[64 * 64];   // W as-is: Wl[k][c]
    const int tid = threadIdx.x;
    const int base = blockIdx.x * 64;

#pragma unroll
    for (int i = 0; i < 16; ++i) {
        int idx = tid + i * 256;
        Wl[idx] = W[idx];
    }
#pragma unroll
    for (int i = 0; i < 16; ++i) {
        int idx = tid + i * 256;
        int r = idx >> 6, k = idx & 63;
        float v = 0.f;
        if (base + r < M) v = A[(size_t)(base + r) * D + k];
        At[k * 68 + r] = v;
    }
    __syncthreads();

    const int tx = tid & 15;        // col group: cols tx*4 .. tx*4+3
    const int ty = tid >> 4;        // row group: rows ty*4 .. ty*4+3

    float acc[4][4] = {};
#pragma unroll
    for (int k = 0; k < 64; ++k) {
        const float4 a4 = *(const float4*)&At[k * 68 + ty * 4];
        const float4 w4 = *(const float4*)&Wl[k * 64 + tx * 4];
        const float a[4] = {a4.x, a4.y, a4.z, a4.w};
        const float w[4] = {w4.x, w4.y, w4.z, w4.w};
#pragma unroll
        for (int i = 0; i < 4; ++i)
#pragma unroll
            for (int j = 0; j < 4; ++j) acc[i][j] += a[i] * w[j];
    }

#pragma unroll
    for (int i = 0; i < 4; ++i) {
        int r = base + ty * 4 + i;
        if (r < M) {
            size_t off = (size_t)r * D + tx * 4;
            float4 v = make_float4(acc[i][0], acc[i][1], acc[i][2], acc[i][3]);
            if (MODE == 1) {
                float4 g = *(const float4*)&gate[off];
                v.x = tanhf(v.x * g.x);
                v.y = tanhf(v.y * g.y);
                v.z = tanhf(v.z * g.z);
                v.w = tanhf(v.w * g.w);
            }
            *(float4*)&C[off] = v;
        }
    }
}

// dst[scatter_idx[i]][:] += src[gather_idx[i]][:], one lane per (incidence, col)
__global__ __launch_bounds__(256) void scatter_add(const float* __restrict__ src,
                                                   const int* __restrict__ gidx,
                                                   const int* __restrict__ sidx,
                                                   float* __restrict__ dst, int n_inc) {
    const int t = blockIdx.x * 256 + threadIdx.x;
    const int inc = t >> 6;
    if (inc >= n_inc) return;
    const int col = t & 63;
    const int g = gidx[inc];
    const int s = sidx[inc];
    atomicAdd(&dst[(size_t)s * D + col], src[(size_t)g * D + col]);
}

extern "C" void kernel_launch(void* const* d_in, const int* in_sizes, int n_in,
                              void* d_out, int out_size, void* d_ws, size_t ws_size,
                              hipStream_t stream) {
    const float* node  = (const float*)d_in[0];
    const float* hedge = (const float*)d_in[1];
    const float* W_nn  = (const float*)d_in[2];
    const float* W_nh  = (const float*)d_in[3];
    const float* W_hh  = (const float*)d_in[4];
    const float* W_hn  = (const float*)d_in[5];
    const int* node_idx  = (const int*)d_in[6];
    const int* hedge_idx = (const int*)d_in[7];

    const int N  = in_sizes[0] / D;   // 200,000 nodes
    const int E  = in_sizes[1] / D;   // 100,000 hedges
    const int NI = in_sizes[6];       // 1,600,000 incidences

    float* out_node  = (float*)d_out;                 // [N, 64]
    float* out_hedge = out_node + (size_t)N * D;      // [E, 64]

    // ws layout: [0 : E*D)   -> hproj, later hgate
    //            [E*D : +N*D) -> ngate, later nproj
    float* hbuf = (float*)d_ws;                       // E*D floats
    float* nbuf = hbuf + (size_t)E * D;               // N*D floats

    const int gbE = (E + 63) / 64;
    const int gbN = (N + 63) / 64;
    const int sb  = (NI + 3) / 4;     // 4 incidences per 256-thread block

    // 1) hproj = hedge @ W_nh
    gemm64<0><<<gbE, 256, 0, stream>>>(hedge, W_nh, nullptr, hbuf, E);
    // 2) ngate = segment_sum
    hipMemsetAsync(nbuf, 0, (size_t)N * D * sizeof(float), stream);
    scatter_add<<<sb, 256, 0, stream>>>(hbuf, hedge_idx, node_idx, nbuf, NI);
    // 3) new_node = tanh((node @ W_nn) * ngate)
    gemm64<1><<<gbN, 256, 0, stream>>>(node, W_nn, nbuf, out_node, N);
    // 4) nproj = new_node @ W_hn  (overwrites ngate buffer)
    gemm64<0><<<gbN, 256, 0, stream>>>(out_node, W_hn, nullptr, nbuf, N);
    // 5) hgate = segment_sum  (reuses hproj buffer)
    hipMemsetAsync(hbuf, 0, (size_t)E * D * sizeof(float), stream);
    scatter_add<<<sb, 256, 0, stream>>>(nbuf, node_idx, hedge_idx, hbuf, NI);
    // 6) new_hedge = tanh((hedge @ W_hh) * hgate)
    gemm64<1><<<gbE, 256, 0, stream>>>(hedge, W_hh, hbuf, out_hedge, E);
}

// Round 2
// 976.184 us; speedup vs baseline: 2.0321x; 2.0321x over previous
//
#include <hip/hip_runtime.h>

#define D 64

__device__ __forceinline__ float fast_tanh(float x) {
    // tanh(x) = 1 - 2/(e^{2x}+1); exp->inf or 0 both give correct saturation
    float e = __expf(2.f * x);
    return 1.f - 2.f * __builtin_amdgcn_rcpf(e + 1.f);
}

// ---------------------------------------------------------------------------
// C[M,64] = A[M,64] @ W[64,64]; MODE 1: C = tanh(C * gate)
// 64-row tile, 256 threads, 4x4 register tile per thread.
// ---------------------------------------------------------------------------
template <int MODE>
__global__ __launch_bounds__(256, 4) void gemm64(const float* __restrict__ A,
                                                 const float* __restrict__ W,
                                                 const float* __restrict__ gate,
                                                 float* __restrict__ C, int M) {
    __shared__ float At[64 * 68];   // A-tile transposed: At[k][r], stride 68
    __shared__ float Wl[64 * 64];   // W: Wl[k][c]
    const int tid = threadIdx.x;
    const int base = blockIdx.x * 64;

#pragma unroll
    for (int i = 0; i < 16; ++i) {
        int idx = tid + i * 256;
        Wl[idx] = W[idx];
        int r = idx >> 6, k = idx & 63;
        float v = 0.f;
        if (base + r < M) v = A[(size_t)(base + r) * D + k];
        At[k * 68 + r] = v;
    }
    __syncthreads();

    const int tx = tid & 15;        // cols tx*4 .. tx*4+3
    const int ty = tid >> 4;        // rows ty*4 .. ty*4+3

    float acc[4][4] = {};
#pragma unroll 4
    for (int k = 0; k < 64; ++k) {
        const float4 a4 = *(const float4*)&At[k * 68 + ty * 4];
        const float4 w4 = *(const float4*)&Wl[k * 64 + tx * 4];
#pragma unroll
        for (int j = 0; j < 4; ++j) {
            const float w = (&w4.x)[j];
            acc[0][j] = fmaf(a4.x, w, acc[0][j]);
            acc[1][j] = fmaf(a4.y, w, acc[1][j]);
            acc[2][j] = fmaf(a4.z, w, acc[2][j]);
            acc[3][j] = fmaf(a4.w, w, acc[3][j]);
        }
    }

#pragma unroll
    for (int i = 0; i < 4; ++i) {
        int r = base + ty * 4 + i;
        if (r < M) {
            size_t off = (size_t)r * D + tx * 4;
            float4 v = make_float4(acc[i][0], acc[i][1], acc[i][2], acc[i][3]);
            if (MODE == 1) {
                float4 g = *(const float4*)&gate[off];
                v.x = fast_tanh(v.x * g.x);
                v.y = fast_tanh(v.y * g.y);
                v.z = fast_tanh(v.z * g.z);
                v.w = fast_tanh(v.w * g.w);
            }
            *(float4*)&C[off] = v;
        }
    }
}

// ---------------------------------------------------------------------------
// Fused: T = tanh((A@W1)*gate)  -> written to OutT [M,64]
//        P = T @ W2             -> written to OutP [M,64]
// Saves a global round-trip of T. gate/OutP may alias (rows only touched by
// owning block; gate read before OutP write).
// ---------------------------------------------------------------------------
__global__ __launch_bounds__(256, 4) void gemm64_fused(const float* __restrict__ A,
                                                       const float* __restrict__ W1,
                                                       const float* __restrict__ W2,
                                                       const float* __restrict__ gate,
                                                       float* __restrict__ OutT,
                                                       float* __restrict__ OutP, int M) {
    __shared__ float At[64 * 68];   // A-tile transposed; reused for T transposed
    __shared__ float W1l[64 * 64];
    __shared__ float W2l[64 * 64];
    const int tid = threadIdx.x;
    const int base = blockIdx.x * 64;

#pragma unroll
    for (int i = 0; i < 16; ++i) {
        int idx = tid + i * 256;
        W1l[idx] = W1[idx];
        W2l[idx] = W2[idx];
        int r = idx >> 6, k = idx & 63;
        float v = 0.f;
        if (base + r < M) v = A[(size_t)(base + r) * D + k];
        At[k * 68 + r] = v;
    }
    __syncthreads();

    const int tx = tid & 15;
    const int ty = tid >> 4;

    float acc[4][4] = {};
#pragma unroll 4
    for (int k = 0; k < 64; ++k) {
        const float4 a4 = *(const float4*)&At[k * 68 + ty * 4];
        const float4 w4 = *(const float4*)&W1l[k * 64 + tx * 4];
#pragma unroll
        for (int j = 0; j < 4; ++j) {
            const float w = (&w4.x)[j];
            acc[0][j] = fmaf(a4.x, w, acc[0][j]);
            acc[1][j] = fmaf(a4.y, w, acc[1][j]);
            acc[2][j] = fmaf(a4.z, w, acc[2][j]);
            acc[3][j] = fmaf(a4.w, w, acc[3][j]);
        }
    }

    // gate + tanh -> T; write OutT; stash T (as acc) for transpose store
#pragma unroll
    for (int i = 0; i < 4; ++i) {
        int r = base + ty * 4 + i;
        if (r < M) {
            size_t off = (size_t)r * D + tx * 4;
            float4 g = *(const float4*)&gate[off];
            acc[i][0] = fast_tanh(acc[i][0] * g.x);
            acc[i][1] = fast_tanh(acc[i][1] * g.y);
            acc[i][2] = fast_tanh(acc[i][2] * g.z);
            acc[i][3] = fast_tanh(acc[i][3] * g.w);
            *(float4*)&OutT[off] = make_float4(acc[i][0], acc[i][1], acc[i][2], acc[i][3]);
        } else {
            acc[i][0] = acc[i][1] = acc[i][2] = acc[i][3] = 0.f;
        }
    }

    __syncthreads();   // everyone done reading At in pass 1
    // store T transposed into At: At[k][r] with k = col of T
#pragma unroll
    for (int j = 0; j < 4; ++j) {
        float4 f = make_float4(acc[0][j], acc[1][j], acc[2][j], acc[3][j]);
        *(float4*)&At[(tx * 4 + j) * 68 + ty * 4] = f;
    }
    __syncthreads();

    float acc2[4][4] = {};
#pragma unroll 4
    for (int k = 0; k < 64; ++k) {
        const float4 a4 = *(const float4*)&At[k * 68 + ty * 4];
        const float4 w4 = *(const float4*)&W2l[k * 64 + tx * 4];
#pragma unroll
        for (int j = 0; j < 4; ++j) {
            const float w = (&w4.x)[j];
            acc2[0][j] = fmaf(a4.x, w, acc2[0][j]);
            acc2[1][j] = fmaf(a4.y, w, acc2[1][j]);
            acc2[2][j] = fmaf(a4.z, w, acc2[2][j]);
            acc2[3][j] = fmaf(a4.w, w, acc2[3][j]);
        }
    }

#pragma unroll
    for (int i = 0; i < 4; ++i) {
        int r = base + ty * 4 + i;
        if (r < M) {
            size_t off = (size_t)r * D + tx * 4;
            *(float4*)&OutP[off] = make_float4(acc2[i][0], acc2[i][1], acc2[i][2], acc2[i][3]);
        }
    }
}

// dst[sidx[i]][:] += src[gidx[i]][:], one lane per (incidence, col)
__global__ __launch_bounds__(256) void scatter_add(const float* __restrict__ src,
                                                   const int* __restrict__ gidx,
                                                   const int* __restrict__ sidx,
                                                   float* __restrict__ dst, int n_inc) {
    const int t = blockIdx.x * 256 + threadIdx.x;
    const int inc = t >> 6;
    if (inc >= n_inc) return;
    const int col = t & 63;
    const int g = gidx[inc];
    const int s = sidx[inc];
    atomicAdd(&dst[(size_t)s * D + col], src[(size_t)g * D + col]);
}

extern "C" void kernel_launch(void* const* d_in, const int* in_sizes, int n_in,
                              void* d_out, int out_size, void* d_ws, size_t ws_size,
                              hipStream_t stream) {
    const float* node  = (const float*)d_in[0];
    const float* hedge = (const float*)d_in[1];
    const float* W_nn  = (const float*)d_in[2];
    const float* W_nh  = (const float*)d_in[3];
    const float* W_hh  = (const float*)d_in[4];
    const float* W_hn  = (const float*)d_in[5];
    const int* node_idx  = (const int*)d_in[6];
    const int* hedge_idx = (const int*)d_in[7];

    const int N  = in_sizes[0] / D;   // 200,000 nodes
    const int E  = in_sizes[1] / D;   // 100,000 hedges
    const int NI = in_sizes[6];       // 1,600,000 incidences

    float* out_node  = (float*)d_out;                 // [N, 64]
    float* out_hedge = out_node + (size_t)N * D;      // [E, 64]

    float* hbuf = (float*)d_ws;                       // E*D floats: hproj -> hgate
    float* nbuf = hbuf + (size_t)E * D;               // N*D floats: ngate -> nproj

    const int gbE = (E + 63) / 64;
    const int gbN = (N + 63) / 64;
    const int sb  = (NI + 3) / 4;     // 4 incidences / 256-thread block

    // 1) hproj = hedge @ W_nh
    gemm64<0><<<gbE, 256, 0, stream>>>(hedge, W_nh, nullptr, hbuf, E);
    // 2) ngate = segment_sum(hproj[hedge_idx], node_idx)
    hipMemsetAsync(nbuf, 0, (size_t)N * D * sizeof(float), stream);
    scatter_add<<<sb, 256, 0, stream>>>(hbuf, hedge_idx, node_idx, nbuf, NI);
    // 3+4) new_node = tanh((node@W_nn)*ngate); nproj = new_node @ W_hn (in nbuf)
    gemm64_fused<<<gbN, 256, 0, stream>>>(node, W_nn, W_hn, nbuf, out_node, nbuf, N);
    // 5) hgate = segment_sum(nproj[node_idx], hedge_idx)
    hipMemsetAsync(hbuf, 0, (size_t)E * D * sizeof(float), stream);
    scatter_add<<<sb, 256, 0, stream>>>(nbuf, node_idx, hedge_idx, hbuf, NI);
    // 6) new_hedge = tanh((hedge @ W_hh) * hgate)
    gemm64<1><<<gbE, 256, 0, stream>>>(hedge, W_hh, hbuf, out_hedge, E);
}

// Round 3
// 840.391 us; speedup vs baseline: 2.3605x; 1.1616x over previous
//
#include <hip/hip_runtime.h>

#define D 64

__device__ __forceinline__ float fast_tanh(float x) {
    float e = __expf(2.f * x);
    return 1.f - 2.f * __builtin_amdgcn_rcpf(e + 1.f);
}

// ---------------------------------------------------------------------------
// C[M,64] = A[M,64] @ W[64,64]; MODE 1: C = tanh(C * gate). gate may alias C.
// ---------------------------------------------------------------------------
template <int MODE>
__global__ __launch_bounds__(256, 4) void gemm64(const float* __restrict__ A,
                                                 const float* __restrict__ W,
                                                 const float* __restrict__ gate,
                                                 float* __restrict__ C, int M) {
    __shared__ float At[64 * 68];
    __shared__ float Wl[64 * 64];
    const int tid = threadIdx.x;
    const int base = blockIdx.x * 64;

#pragma unroll
    for (int i = 0; i < 16; ++i) {
        int idx = tid + i * 256;
        Wl[idx] = W[idx];
        int r = idx >> 6, k = idx & 63;
        float v = 0.f;
        if (base + r < M) v = A[(size_t)(base + r) * D + k];
        At[k * 68 + r] = v;
    }
    __syncthreads();

    const int tx = tid & 15;
    const int ty = tid >> 4;

    float acc[4][4] = {};
#pragma unroll 4
    for (int k = 0; k < 64; ++k) {
        const float4 a4 = *(const float4*)&At[k * 68 + ty * 4];
        const float4 w4 = *(const float4*)&Wl[k * 64 + tx * 4];
#pragma unroll
        for (int j = 0; j < 4; ++j) {
            const float w = (&w4.x)[j];
            acc[0][j] = fmaf(a4.x, w, acc[0][j]);
            acc[1][j] = fmaf(a4.y, w, acc[1][j]);
            acc[2][j] = fmaf(a4.z, w, acc[2][j]);
            acc[3][j] = fmaf(a4.w, w, acc[3][j]);
        }
    }

#pragma unroll
    for (int i = 0; i < 4; ++i) {
        int r = base + ty * 4 + i;
        if (r < M) {
            size_t off = (size_t)r * D + tx * 4;
            float4 v = make_float4(acc[i][0], acc[i][1], acc[i][2], acc[i][3]);
            if (MODE == 1) {
                float4 g = *(const float4*)&gate[off];
                v.x = fast_tanh(v.x * g.x);
                v.y = fast_tanh(v.y * g.y);
                v.z = fast_tanh(v.z * g.z);
                v.w = fast_tanh(v.w * g.w);
            }
            *(float4*)&C[off] = v;
        }
    }
}

// ---------------------------------------------------------------------------
// Fused: T = tanh((A@W1)*gate) -> OutT; P = T @ W2 -> OutP (gate may alias OutP)
// ---------------------------------------------------------------------------
__global__ __launch_bounds__(256, 4) void gemm64_fused(const float* __restrict__ A,
                                                       const float* __restrict__ W1,
                                                       const float* __restrict__ W2,
                                                       const float* __restrict__ gate,
                                                       float* __restrict__ OutT,
                                                       float* __restrict__ OutP, int M) {
    __shared__ float At[64 * 68];
    __shared__ float W1l[64 * 64];
    __shared__ float W2l[64 * 64];
    const int tid = threadIdx.x;
    const int base = blockIdx.x * 64;

#pragma unroll
    for (int i = 0; i < 16; ++i) {
        int idx = tid + i * 256;
        W1l[idx] = W1[idx];
        W2l[idx] = W2[idx];
        int r = idx >> 6, k = idx & 63;
        float v = 0.f;
        if (base + r < M) v = A[(size_t)(base + r) * D + k];
        At[k * 68 + r] = v;
    }
    __syncthreads();

    const int tx = tid & 15;
    const int ty = tid >> 4;

    float acc[4][4] = {};
#pragma unroll 4
    for (int k = 0; k < 64; ++k) {
        const float4 a4 = *(const float4*)&At[k * 68 + ty * 4];
        const float4 w4 = *(const float4*)&W1l[k * 64 + tx * 4];
#pragma unroll
        for (int j = 0; j < 4; ++j) {
            const float w = (&w4.x)[j];
            acc[0][j] = fmaf(a4.x, w, acc[0][j]);
            acc[1][j] = fmaf(a4.y, w, acc[1][j]);
            acc[2][j] = fmaf(a4.z, w, acc[2][j]);
            acc[3][j] = fmaf(a4.w, w, acc[3][j]);
        }
    }

#pragma unroll
    for (int i = 0; i < 4; ++i) {
        int r = base + ty * 4 + i;
        if (r < M) {
            size_t off = (size_t)r * D + tx * 4;
            float4 g = *(const float4*)&gate[off];
            acc[i][0] = fast_tanh(acc[i][0] * g.x);
            acc[i][1] = fast_tanh(acc[i][1] * g.y);
            acc[i][2] = fast_tanh(acc[i][2] * g.z);
            acc[i][3] = fast_tanh(acc[i][3] * g.w);
            *(float4*)&OutT[off] = make_float4(acc[i][0], acc[i][1], acc[i][2], acc[i][3]);
        } else {
            acc[i][0] = acc[i][1] = acc[i][2] = acc[i][3] = 0.f;
        }
    }

    __syncthreads();
#pragma unroll
    for (int j = 0; j < 4; ++j) {
        float4 f = make_float4(acc[0][j], acc[1][j], acc[2][j], acc[3][j]);
        *(float4*)&At[(tx * 4 + j) * 68 + ty * 4] = f;
    }
    __syncthreads();

    float acc2[4][4] = {};
#pragma unroll 4
    for (int k = 0; k < 64; ++k) {
        const float4 a4 = *(const float4*)&At[k * 68 + ty * 4];
        const float4 w4 = *(const float4*)&W2l[k * 64 + tx * 4];
#pragma unroll
        for (int j = 0; j < 4; ++j) {
            const float w = (&w4.x)[j];
            acc2[0][j] = fmaf(a4.x, w, acc2[0][j]);
            acc2[1][j] = fmaf(a4.y, w, acc2[1][j]);
            acc2[2][j] = fmaf(a4.z, w, acc2[2][j]);
            acc2[3][j] = fmaf(a4.w, w, acc2[3][j]);
        }
    }

#pragma unroll
    for (int i = 0; i < 4; ++i) {
        int r = base + ty * 4 + i;
        if (r < M) {
            size_t off = (size_t)r * D + tx * 4;
            *(float4*)&OutP[off] = make_float4(acc2[i][0], acc2[i][1], acc2[i][2], acc2[i][3]);
        }
    }
}

// --------------------------- CSR build ------------------------------------
__global__ __launch_bounds__(256) void hist_kernel(const int* __restrict__ idx,
                                                   int* __restrict__ counts, int n) {
    int i = blockIdx.x * 256 + threadIdx.x;
    if (i < n) atomicAdd(&counts[idx[i]], 1);
}

// per-block (1024-elem) exclusive scan; block total -> bsums
__global__ __launch_bounds__(256) void scan1(const int* __restrict__ counts,
                                             int* __restrict__ offs,
                                             int* __restrict__ bsums, int n) {
    __shared__ int s[256];
    const int t = threadIdx.x;
    const int base = blockIdx.x * 1024 + t * 4;
    int v[4];
#pragma unroll
    for (int j = 0; j < 4; ++j) v[j] = (base + j < n) ? counts[base + j] : 0;
    int tsum = v[0] + v[1] + v[2] + v[3];
    s[t] = tsum;
    __syncthreads();
    for (int o = 1; o < 256; o <<= 1) {
        int x = (t >= o) ? s[t - o] : 0;
        __syncthreads();
        s[t] += x;
        __syncthreads();
    }
    int excl = s[t] - tsum;
    if (t == 255) bsums[blockIdx.x] = s[255];
    int run = excl;
#pragma unroll
    for (int j = 0; j < 4; ++j) {
        if (base + j < n) offs[base + j] = run;
        run += v[j];
    }
}

// exclusive scan of block sums (nb <= 256), in place
__global__ __launch_bounds__(256) void scan2(int* __restrict__ bsums, int nb) {
    __shared__ int s[256];
    const int t = threadIdx.x;
    int v = (t < nb) ? bsums[t] : 0;
    s[t] = v;
    __syncthreads();
    for (int o = 1; o < 256; o <<= 1) {
        int x = (t >= o) ? s[t - o] : 0;
        __syncthreads();
        s[t] += x;
        __syncthreads();
    }
    if (t < nb) bsums[t] = s[t] - v;
}

// add block base; write offs and cursor copy
__global__ __launch_bounds__(256) void scan3(int* __restrict__ offs,
                                             int* __restrict__ cursor,
                                             const int* __restrict__ bsums, int n) {
    int i = blockIdx.x * 256 + threadIdx.x;
    if (i < n) {
        int v = offs[i] + bsums[i >> 10];
        offs[i] = v;
        cursor[i] = v;
    }
}

__global__ __launch_bounds__(256) void fill_kernel(const int* __restrict__ didx,
                                                   const int* __restrict__ gidx,
                                                   int* __restrict__ cursor,
                                                   int* __restrict__ csr, int n) {
    int i = blockIdx.x * 256 + threadIdx.x;
    if (i < n) {
        int p = atomicAdd(&cursor[didx[i]], 1);
        csr[p] = gidx[i];
    }
}

// dst[r,:] = sum over csr[offs[r] .. offs[r]+counts[r]) of src[csr[j],:]
// one wave per row, lane = column
__global__ __launch_bounds__(256) void gather_rows(const float* __restrict__ src,
                                                   const int* __restrict__ csr,
                                                   const int* __restrict__ offs,
                                                   const int* __restrict__ counts,
                                                   float* __restrict__ dst, int nrows) {
    const int wave = (blockIdx.x * 256 + threadIdx.x) >> 6;
    const int lane = threadIdx.x & 63;
    if (wave >= nrows) return;
    const int start = offs[wave];
    const int deg = counts[wave];
    float acc0 = 0.f, acc1 = 0.f;
    int j = 0;
    for (; j + 1 < deg; j += 2) {
        int s0 = csr[start + j];
        int s1 = csr[start + j + 1];
        acc0 += src[((size_t)s0 << 6) + lane];
        acc1 += src[((size_t)s1 << 6) + lane];
    }
    if (j < deg) {
        int s0 = csr[start + j];
        acc0 += src[((size_t)s0 << 6) + lane];
    }
    dst[((size_t)wave << 6) + lane] = acc0 + acc1;
}

extern "C" void kernel_launch(void* const* d_in, const int* in_sizes, int n_in,
                              void* d_out, int out_size, void* d_ws, size_t ws_size,
                              hipStream_t stream) {
    const float* node  = (const float*)d_in[0];
    const float* hedge = (const float*)d_in[1];
    const float* W_nn  = (const float*)d_in[2];
    const float* W_nh  = (const float*)d_in[3];
    const float* W_hh  = (const float*)d_in[4];
    const float* W_hn  = (const float*)d_in[5];
    const int* node_idx  = (const int*)d_in[6];
    const int* hedge_idx = (const int*)d_in[7];

    const int N  = in_sizes[0] / D;   // 200,000
    const int E  = in_sizes[1] / D;   // 100,000
    const int NI = in_sizes[6];       // 1,600,000
    const int maxNE = (N > E) ? N : E;

    float* out_node  = (float*)d_out;                  // [N,64]
    float* out_hedge = out_node + (size_t)N * D;       // [E,64] — also scratch for hproj/hgate

    // ws: nbuf (N*D f32) | csr (NI i32) | offs | cursor | counts | bsums
    float* nbuf   = (float*)d_ws;
    int*   csr    = (int*)(nbuf + (size_t)N * D);
    int*   offs   = csr + NI;
    int*   cursor = offs + maxNE;
    int*   counts = cursor + maxNE;
    int*   bsums  = counts + maxNE;

    const int gbE = (E + 63) / 64;
    const int gbN = (N + 63) / 64;
    const int ib  = (NI + 255) / 256;

    // ---------- phase 1: ngate[n] = sum hproj[hedge_idx] over incidences ----------
    hipMemsetAsync(counts, 0, (size_t)N * sizeof(int), stream);
    hist_kernel<<<ib, 256, 0, stream>>>(node_idx, counts, NI);
    scan1<<<(N + 1023) / 1024, 256, 0, stream>>>(counts, offs, bsums, N);
    scan2<<<1, 256, 0, stream>>>(bsums, (N + 1023) / 1024);
    scan3<<<(N + 255) / 256, 256, 0, stream>>>(offs, cursor, bsums, N);
    fill_kernel<<<ib, 256, 0, stream>>>(node_idx, hedge_idx, cursor, csr, NI);

    gemm64<0><<<gbE, 256, 0, stream>>>(hedge, W_nh, nullptr, out_hedge /*hproj*/, E);
    gather_rows<<<(N + 3) / 4, 256, 0, stream>>>(out_hedge, csr, offs, counts, nbuf /*ngate*/, N);

    // new_node = tanh((node@W_nn)*ngate); nproj = new_node@W_hn -> nbuf
    gemm64_fused<<<gbN, 256, 0, stream>>>(node, W_nn, W_hn, nbuf, out_node, nbuf, N);

    // ---------- phase 2: hgate[e] = sum nproj[node_idx] over incidences ----------
    hipMemsetAsync(counts, 0, (size_t)E * sizeof(int), stream);
    hist_kernel<<<ib, 256, 0, stream>>>(hedge_idx, counts, NI);
    scan1<<<(E + 1023) / 1024, 256, 0, stream>>>(counts, offs, bsums, E);
    scan2<<<1, 256, 0, stream>>>(bsums, (E + 1023) / 1024);
    scan3<<<(E + 255) / 256, 256, 0, stream>>>(offs, cursor, bsums, E);
    fill_kernel<<<ib, 256, 0, stream>>>(hedge_idx, node_idx, cursor, csr, NI);

    gather_rows<<<(E + 3) / 4, 256, 0, stream>>>(nbuf /*nproj*/, csr, offs, counts, out_hedge /*hgate*/, E);

    // new_hedge = tanh((hedge@W_hh)*hgate), in place over hgate
    gemm64<1><<<gbE, 256, 0, stream>>>(hedge, W_hh, out_hedge, out_hedge, E);
}

// Round 4
// 567.724 us; speedup vs baseline: 3.4942x; 1.4803x over previous
//
#include <hip/hip_runtime.h>

#define D 64
#define SH 8              // bucket = key >> SH; local key = key & 255
#define NBLK 256          // blocks for sort passes A1/A2

__device__ __forceinline__ float fast_tanh(float x) {
    float e = __expf(2.f * x);
    return 1.f - 2.f * __builtin_amdgcn_rcpf(e + 1.f);
}

// ---------------------------------------------------------------------------
// C[M,64] = A[M,64] @ W[64,64]; MODE 1: C = tanh(C * gate). gate may alias C.
// ---------------------------------------------------------------------------
template <int MODE>
__global__ __launch_bounds__(256, 4) void gemm64(const float* __restrict__ A,
                                                 const float* __restrict__ W,
                                                 const float* __restrict__ gate,
                                                 float* __restrict__ C, int M) {
    __shared__ float At[64 * 68];
    __shared__ float Wl[64 * 64];
    const int tid = threadIdx.x;
    const int base = blockIdx.x * 64;

#pragma unroll
    for (int i = 0; i < 16; ++i) {
        int idx = tid + i * 256;
        Wl[idx] = W[idx];
        int r = idx >> 6, k = idx & 63;
        float v = 0.f;
        if (base + r < M) v = A[(size_t)(base + r) * D + k];
        At[k * 68 + r] = v;
    }
    __syncthreads();

    const int tx = tid & 15;
    const int ty = tid >> 4;

    float acc[4][4] = {};
#pragma unroll 4
    for (int k = 0; k < 64; ++k) {
        const float4 a4 = *(const float4*)&At[k * 68 + ty * 4];
        const float4 w4 = *(const float4*)&Wl[k * 64 + tx * 4];
#pragma unroll
        for (int j = 0; j < 4; ++j) {
            const float w = (&w4.x)[j];
            acc[0][j] = fmaf(a4.x, w, acc[0][j]);
            acc[1][j] = fmaf(a4.y, w, acc[1][j]);
            acc[2][j] = fmaf(a4.z, w, acc[2][j]);
            acc[3][j] = fmaf(a4.w, w, acc[3][j]);
        }
    }

#pragma unroll
    for (int i = 0; i < 4; ++i) {
        int r = base + ty * 4 + i;
        if (r < M) {
            size_t off = (size_t)r * D + tx * 4;
            float4 v = make_float4(acc[i][0], acc[i][1], acc[i][2], acc[i][3]);
            if (MODE == 1) {
                float4 g = *(const float4*)&gate[off];
                v.x = fast_tanh(v.x * g.x);
                v.y = fast_tanh(v.y * g.y);
                v.z = fast_tanh(v.z * g.z);
                v.w = fast_tanh(v.w * g.w);
            }
            *(float4*)&C[off] = v;
        }
    }
}

// ---------------------------------------------------------------------------
// Dual GEMM: C = tanh((A1@W1) * (A2@W2)), all [*,64]x[64,64]
// ---------------------------------------------------------------------------
__global__ __launch_bounds__(256, 2) void gemm64_dual(const float* __restrict__ A1,
                                                      const float* __restrict__ W1,
                                                      const float* __restrict__ A2,
                                                      const float* __restrict__ W2,
                                                      float* __restrict__ C, int M) {
    __shared__ float At1[64 * 68];
    __shared__ float At2[64 * 68];
    __shared__ float W1l[64 * 64];
    __shared__ float W2l[64 * 64];
    const int tid = threadIdx.x;
    const int base = blockIdx.x * 64;

#pragma unroll
    for (int i = 0; i < 16; ++i) {
        int idx = tid + i * 256;
        W1l[idx] = W1[idx];
        W2l[idx] = W2[idx];
        int r = idx >> 6, k = idx & 63;
        float v1 = 0.f, v2 = 0.f;
        if (base + r < M) {
            v1 = A1[(size_t)(base + r) * D + k];
            v2 = A2[(size_t)(base + r) * D + k];
        }
        At1[k * 68 + r] = v1;
        At2[k * 68 + r] = v2;
    }
    __syncthreads();

    const int tx = tid & 15;
    const int ty = tid >> 4;

    float acc1[4][4] = {};
    float acc2[4][4] = {};
#pragma unroll 2
    for (int k = 0; k < 64; ++k) {
        const float4 a1 = *(const float4*)&At1[k * 68 + ty * 4];
        const float4 w1 = *(const float4*)&W1l[k * 64 + tx * 4];
        const float4 a2 = *(const float4*)&At2[k * 68 + ty * 4];
        const float4 w2 = *(const float4*)&W2l[k * 64 + tx * 4];
#pragma unroll
        for (int j = 0; j < 4; ++j) {
            const float u = (&w1.x)[j];
            acc1[0][j] = fmaf(a1.x, u, acc1[0][j]);
            acc1[1][j] = fmaf(a1.y, u, acc1[1][j]);
            acc1[2][j] = fmaf(a1.z, u, acc1[2][j]);
            acc1[3][j] = fmaf(a1.w, u, acc1[3][j]);
            const float v = (&w2.x)[j];
            acc2[0][j] = fmaf(a2.x, v, acc2[0][j]);
            acc2[1][j] = fmaf(a2.y, v, acc2[1][j]);
            acc2[2][j] = fmaf(a2.z, v, acc2[2][j]);
            acc2[3][j] = fmaf(a2.w, v, acc2[3][j]);
        }
    }

#pragma unroll
    for (int i = 0; i < 4; ++i) {
        int r = base + ty * 4 + i;
        if (r < M) {
            size_t off = (size_t)r * D + tx * 4;
            float4 v;
            v.x = fast_tanh(acc1[i][0] * acc2[i][0]);
            v.y = fast_tanh(acc1[i][1] * acc2[i][1]);
            v.z = fast_tanh(acc1[i][2] * acc2[i][2]);
            v.w = fast_tanh(acc1[i][3] * acc2[i][3]);
            *(float4*)&C[off] = v;
        }
    }
}

// --------------------- zero-global-atomic counting sort ---------------------
// Pass A1: per-block histogram of buckets -> cmat[b*NBLK + blk]
__global__ __launch_bounds__(256) void sort_hist(const int* __restrict__ keys,
                                                 int* __restrict__ cmat,
                                                 int n, int B, int ipb) {
    __shared__ int h[1024];
    const int tid = threadIdx.x;
    for (int i = tid; i < B; i += 256) h[i] = 0;
    __syncthreads();
    const int start = blockIdx.x * ipb;
    const int end = (start + ipb < n) ? start + ipb : n;
    for (int i = start + tid; i < end; i += 256)
        atomicAdd(&h[keys[i] >> SH], 1);
    __syncthreads();
    for (int b = tid; b < B; b += 256) cmat[b * NBLK + blockIdx.x] = h[b];
}

// per-1024 exclusive scan; block total -> bsums
__global__ __launch_bounds__(256) void scan1(const int* __restrict__ src,
                                             int* __restrict__ dst,
                                             int* __restrict__ bsums, int n) {
    __shared__ int s[256];
    const int t = threadIdx.x;
    const int base = blockIdx.x * 1024 + t * 4;
    int v[4];
#pragma unroll
    for (int j = 0; j < 4; ++j) v[j] = (base + j < n) ? src[base + j] : 0;
    int tsum = v[0] + v[1] + v[2] + v[3];
    s[t] = tsum;
    __syncthreads();
    for (int o = 1; o < 256; o <<= 1) {
        int x = (t >= o) ? s[t - o] : 0;
        __syncthreads();
        s[t] += x;
        __syncthreads();
    }
    int run = s[t] - tsum;
    if (t == 255) bsums[blockIdx.x] = s[255];
#pragma unroll
    for (int j = 0; j < 4; ++j) {
        if (base + j < n) dst[base + j] = run;
        run += v[j];
    }
}

__global__ __launch_bounds__(256) void scan2(int* __restrict__ bsums, int nb) {
    __shared__ int s[256];
    const int t = threadIdx.x;
    int v = (t < nb) ? bsums[t] : 0;
    s[t] = v;
    __syncthreads();
    for (int o = 1; o < 256; o <<= 1) {
        int x = (t >= o) ? s[t - o] : 0;
        __syncthreads();
        s[t] += x;
        __syncthreads();
    }
    if (t < nb) bsums[t] = s[t] - v;
}

__global__ __launch_bounds__(256) void scan3(int* __restrict__ a,
                                             const int* __restrict__ bsums, int n) {
    int i = blockIdx.x * 256 + threadIdx.x;
    if (i < n) a[i] += bsums[i >> 10];
}

// Pass A2: scatter packed (val<<8 | key&255) into bucket-contiguous slots
__global__ __launch_bounds__(256) void sort_scatter(const int* __restrict__ keys,
                                                    const int* __restrict__ vals,
                                                    const int* __restrict__ cscan,
                                                    int* __restrict__ bucketed,
                                                    int n, int B, int ipb) {
    __shared__ int cur[1024];
    const int tid = threadIdx.x;
    for (int i = tid; i < B; i += 256) cur[i] = cscan[i * NBLK + blockIdx.x];
    __syncthreads();
    const int start = blockIdx.x * ipb;
    const int end = (start + ipb < n) ? start + ipb : n;
    for (int i = start + tid; i < end; i += 256) {
        int k = keys[i];
        int p = atomicAdd(&cur[k >> SH], 1);
        bucketed[p] = (vals[i] << 8) | (k & 255);
    }
}

// Pass B: per-bucket exact CSR (grid = B blocks)
__global__ __launch_bounds__(256) void sort_finalize(const int* __restrict__ bucketed,
                                                     const int* __restrict__ cscan,
                                                     int* __restrict__ csr,
                                                     int* __restrict__ offs,
                                                     int* __restrict__ counts,
                                                     int n, int B, int nkeys) {
    __shared__ int s[256];
    __shared__ int cur[256];
    const int t = threadIdx.x;
    const int b = blockIdx.x;
    const int bstart = cscan[b * NBLK];
    const int bend = (b + 1 < B) ? cscan[(b + 1) * NBLK] : n;

    cur[t] = 0;
    __syncthreads();
    for (int i = bstart + t; i < bend; i += 256)
        atomicAdd(&cur[bucketed[i] & 255], 1);
    __syncthreads();
    const int cnt = cur[t];
    s[t] = cnt;
    __syncthreads();
    for (int o = 1; o < 256; o <<= 1) {
        int x = (t >= o) ? s[t - o] : 0;
        __syncthreads();
        s[t] += x;
        __syncthreads();
    }
    const int excl = s[t] - cnt;
    const int key = (b << SH) + t;
    if (key < nkeys) {
        offs[key] = bstart + excl;
        counts[key] = cnt;
    }
    __syncthreads();
    cur[t] = bstart + excl;
    __syncthreads();
    for (int i = bstart + t; i < bend; i += 256) {
        int e = bucketed[i];
        int p = atomicAdd(&cur[e & 255], 1);
        csr[p] = e >> 8;
    }
}

// dst[r,:] = sum of src[csr[j],:] for j in [offs[r], offs[r]+counts[r])
__global__ __launch_bounds__(256) void gather_rows(const float* __restrict__ src,
                                                   const int* __restrict__ csr,
                                                   const int* __restrict__ offs,
                                                   const int* __restrict__ counts,
                                                   float* __restrict__ dst, int nrows) {
    const int wave = (blockIdx.x * 256 + threadIdx.x) >> 6;
    const int lane = threadIdx.x & 63;
    if (wave >= nrows) return;
    const int start = offs[wave];
    const int deg = counts[wave];
    float acc0 = 0.f, acc1 = 0.f;
    int j = 0;
    for (; j + 1 < deg; j += 2) {
        int s0 = csr[start + j];
        int s1 = csr[start + j + 1];
        acc0 += src[((size_t)s0 << 6) + lane];
        acc1 += src[((size_t)s1 << 6) + lane];
    }
    if (j < deg) acc0 += src[((size_t)csr[start + j] << 6) + lane];
    dst[((size_t)wave << 6) + lane] = acc0 + acc1;
}

// Build CSR grouping `keys` (dest) with payload `vals` (src), no global atomics.
static void build_csr(const int* keys, const int* vals, int NI, int nkeys,
                      int* cmat, int* cscan, int* bsums, int* bucketed,
                      int* csr, int* offs, int* counts, hipStream_t stream) {
    const int B = (nkeys + 255) >> SH;        // buckets
    const int L = B * NBLK;                   // cmat length (<= 262144)
    const int ipb = (NI + NBLK - 1) / NBLK;
    sort_hist<<<NBLK, 256, 0, stream>>>(keys, cmat, NI, B, ipb);
    scan1<<<(L + 1023) / 1024, 256, 0, stream>>>(cmat, cscan, bsums, L);
    scan2<<<1, 256, 0, stream>>>(bsums, (L + 1023) / 1024);
    scan3<<<(L + 255) / 256, 256, 0, stream>>>(cscan, bsums, L);
    sort_scatter<<<NBLK, 256, 0, stream>>>(keys, vals, cscan, bucketed, NI, B, ipb);
    sort_finalize<<<B, 256, 0, stream>>>(bucketed, cscan, csr, offs, counts, NI, B, nkeys);
}

extern "C" void kernel_launch(void* const* d_in, const int* in_sizes, int n_in,
                              void* d_out, int out_size, void* d_ws, size_t ws_size,
                              hipStream_t stream) {
    const float* node  = (const float*)d_in[0];
    const float* hedge = (const float*)d_in[1];
    const float* W_nn  = (const float*)d_in[2];
    const float* W_nh  = (const float*)d_in[3];
    const float* W_hh  = (const float*)d_in[4];
    const float* W_hn  = (const float*)d_in[5];
    const int* node_idx  = (const int*)d_in[6];
    const int* hedge_idx = (const int*)d_in[7];

    const int N  = in_sizes[0] / D;   // 200,000
    const int E  = in_sizes[1] / D;   // 100,000
    const int NI = in_sizes[6];       // 1,600,000
    const int maxNE = (N > E) ? N : E;
    const int maxB = (maxNE + 255) >> SH;

    float* out_node  = (float*)d_out;                  // [N,64]
    float* out_hedge = out_node + (size_t)N * D;       // [E,64] (also hproj scratch)

    // ws: nbuf[N*D f32] | bucketed[NI] | csr[NI] | cmat[maxB*NBLK] | cscan[...] |
    //     offs[maxNE] | counts[maxNE] | bsums[256]
    float* nbuf     = (float*)d_ws;
    int*   bucketed = (int*)(nbuf + (size_t)N * D);
    int*   csr      = bucketed + NI;
    int*   cmat     = csr + NI;
    int*   cscan    = cmat + (size_t)maxB * NBLK;
    int*   offs     = cscan + (size_t)maxB * NBLK;
    int*   counts   = offs + maxNE;
    int*   bsums    = counts + maxNE;

    const int gbE = (E + 63) / 64;
    const int gbN = (N + 63) / 64;

    // ---------- phase 1 ----------
    build_csr(node_idx, hedge_idx, NI, N, cmat, cscan, bsums, bucketed,
              csr, offs, counts, stream);
    // hproj = hedge @ W_nh (scratch in out_hedge)
    gemm64<0><<<gbE, 256, 0, stream>>>(hedge, W_nh, nullptr, out_hedge, E);
    // ngate = segment-gather(hproj)
    gather_rows<<<(N + 3) / 4, 256, 0, stream>>>(out_hedge, csr, offs, counts, nbuf, N);
    // new_node = tanh((node@W_nn) * ngate)
    gemm64<1><<<gbN, 256, 0, stream>>>(node, W_nn, nbuf, out_node, N);

    // ---------- phase 2 (reassociated: hgate = (Mt @ new_node) @ W_hn) ----------
    build_csr(hedge_idx, node_idx, NI, E, cmat, cscan, bsums, bucketed,
              csr, offs, counts, stream);
    // agg = segment-gather(new_node)  -> nbuf[0 : E*64)
    gather_rows<<<(E + 3) / 4, 256, 0, stream>>>(out_node, csr, offs, counts, nbuf, E);
    // new_hedge = tanh((hedge@W_hh) * (agg@W_hn))
    gemm64_dual<<<gbE, 256, 0, stream>>>(hedge, W_hh, nbuf, W_hn, out_hedge, E);
}

// Round 5
// 503.822 us; speedup vs baseline: 3.9374x; 1.1268x over previous
//
#include <hip/hip_runtime.h>

#define D 64
#define SH 8              // bucket = key >> SH
#define NBLK 256          // blocks for sort passes A1/A2

typedef _Float16 half4v __attribute__((ext_vector_type(4)));

__device__ __forceinline__ float fast_tanh(float x) {
    float e = __expf(2.f * x);
    return 1.f - 2.f * __builtin_amdgcn_rcpf(e + 1.f);
}

// ---------------------------------------------------------------------------
// C[M,64] = A[M,64] @ W[64,64].
// GATE: C = tanh(C * gate) (gate may alias Cf). WF: write fp32 Cf. WH: write fp16 Ch.
// ---------------------------------------------------------------------------
template <int GATE, int WF, int WH>
__global__ __launch_bounds__(256, 4) void gemm64(const float* __restrict__ A,
                                                 const float* __restrict__ W,
                                                 const float* __restrict__ gate,
                                                 float* __restrict__ Cf,
                                                 _Float16* __restrict__ Ch, int M) {
    __shared__ float At[64 * 68];
    __shared__ float Wl[64 * 64];
    const int tid = threadIdx.x;
    const int base = blockIdx.x * 64;

#pragma unroll
    for (int i = 0; i < 16; ++i) {
        int idx = tid + i * 256;
        Wl[idx] = W[idx];
        int r = idx >> 6, k = idx & 63;
        float v = 0.f;
        if (base + r < M) v = A[(size_t)(base + r) * D + k];
        At[k * 68 + r] = v;
    }
    __syncthreads();

    const int tx = tid & 15;
    const int ty = tid >> 4;

    float acc[4][4] = {};
#pragma unroll 4
    for (int k = 0; k < 64; ++k) {
        const float4 a4 = *(const float4*)&At[k * 68 + ty * 4];
        const float4 w4 = *(const float4*)&Wl[k * 64 + tx * 4];
#pragma unroll
        for (int j = 0; j < 4; ++j) {
            const float w = (&w4.x)[j];
            acc[0][j] = fmaf(a4.x, w, acc[0][j]);
            acc[1][j] = fmaf(a4.y, w, acc[1][j]);
            acc[2][j] = fmaf(a4.z, w, acc[2][j]);
            acc[3][j] = fmaf(a4.w, w, acc[3][j]);
        }
    }

#pragma unroll
    for (int i = 0; i < 4; ++i) {
        int r = base + ty * 4 + i;
        if (r < M) {
            size_t off = (size_t)r * D + tx * 4;
            float4 v = make_float4(acc[i][0], acc[i][1], acc[i][2], acc[i][3]);
            if (GATE) {
                float4 g = *(const float4*)&gate[off];
                v.x = fast_tanh(v.x * g.x);
                v.y = fast_tanh(v.y * g.y);
                v.z = fast_tanh(v.z * g.z);
                v.w = fast_tanh(v.w * g.w);
            }
            if (WF) *(float4*)&Cf[off] = v;
            if (WH) {
                half4v h;
                h.x = (_Float16)v.x; h.y = (_Float16)v.y;
                h.z = (_Float16)v.z; h.w = (_Float16)v.w;
                *(half4v*)&Ch[off] = h;
            }
        }
    }
}

// ---------------------------------------------------------------------------
// Dual GEMM: C = tanh((A1@W1) * (A2@W2))
// ---------------------------------------------------------------------------
__global__ __launch_bounds__(256, 2) void gemm64_dual(const float* __restrict__ A1,
                                                      const float* __restrict__ W1,
                                                      const float* __restrict__ A2,
                                                      const float* __restrict__ W2,
                                                      float* __restrict__ C, int M) {
    __shared__ float At1[64 * 68];
    __shared__ float At2[64 * 68];
    __shared__ float W1l[64 * 64];
    __shared__ float W2l[64 * 64];
    const int tid = threadIdx.x;
    const int base = blockIdx.x * 64;

#pragma unroll
    for (int i = 0; i < 16; ++i) {
        int idx = tid + i * 256;
        W1l[idx] = W1[idx];
        W2l[idx] = W2[idx];
        int r = idx >> 6, k = idx & 63;
        float v1 = 0.f, v2 = 0.f;
        if (base + r < M) {
            v1 = A1[(size_t)(base + r) * D + k];
            v2 = A2[(size_t)(base + r) * D + k];
        }
        At1[k * 68 + r] = v1;
        At2[k * 68 + r] = v2;
    }
    __syncthreads();

    const int tx = tid & 15;
    const int ty = tid >> 4;

    float acc1[4][4] = {};
    float acc2[4][4] = {};
#pragma unroll 2
    for (int k = 0; k < 64; ++k) {
        const float4 a1 = *(const float4*)&At1[k * 68 + ty * 4];
        const float4 w1 = *(const float4*)&W1l[k * 64 + tx * 4];
        const float4 a2 = *(const float4*)&At2[k * 68 + ty * 4];
        const float4 w2 = *(const float4*)&W2l[k * 64 + tx * 4];
#pragma unroll
        for (int j = 0; j < 4; ++j) {
            const float u = (&w1.x)[j];
            acc1[0][j] = fmaf(a1.x, u, acc1[0][j]);
            acc1[1][j] = fmaf(a1.y, u, acc1[1][j]);
            acc1[2][j] = fmaf(a1.z, u, acc1[2][j]);
            acc1[3][j] = fmaf(a1.w, u, acc1[3][j]);
            const float v = (&w2.x)[j];
            acc2[0][j] = fmaf(a2.x, v, acc2[0][j]);
            acc2[1][j] = fmaf(a2.y, v, acc2[1][j]);
            acc2[2][j] = fmaf(a2.z, v, acc2[2][j]);
            acc2[3][j] = fmaf(a2.w, v, acc2[3][j]);
        }
    }

#pragma unroll
    for (int i = 0; i < 4; ++i) {
        int r = base + ty * 4 + i;
        if (r < M) {
            size_t off = (size_t)r * D + tx * 4;
            float4 v;
            v.x = fast_tanh(acc1[i][0] * acc2[i][0]);
            v.y = fast_tanh(acc1[i][1] * acc2[i][1]);
            v.z = fast_tanh(acc1[i][2] * acc2[i][2]);
            v.w = fast_tanh(acc1[i][3] * acc2[i][3]);
            *(float4*)&C[off] = v;
        }
    }
}

// --------------------- zero-global-atomic counting sort ---------------------
__global__ __launch_bounds__(256) void sort_hist(const int* __restrict__ keys,
                                                 int* __restrict__ cmat,
                                                 int n, int B, int ipb) {
    __shared__ int h[1024];
    const int tid = threadIdx.x;
    for (int i = tid; i < B; i += 256) h[i] = 0;
    __syncthreads();
    const int start = blockIdx.x * ipb;
    const int end = (start + ipb < n) ? start + ipb : n;
    for (int i = start + tid; i < end; i += 256)
        atomicAdd(&h[keys[i] >> SH], 1);
    __syncthreads();
    for (int b = tid; b < B; b += 256) cmat[b * NBLK + blockIdx.x] = h[b];
}

__global__ __launch_bounds__(256) void scan1(const int* __restrict__ src,
                                             int* __restrict__ dst,
                                             int* __restrict__ bsums, int n) {
    __shared__ int s[256];
    const int t = threadIdx.x;
    const int base = blockIdx.x * 1024 + t * 4;
    int v[4];
#pragma unroll
    for (int j = 0; j < 4; ++j) v[j] = (base + j < n) ? src[base + j] : 0;
    int tsum = v[0] + v[1] + v[2] + v[3];
    s[t] = tsum;
    __syncthreads();
    for (int o = 1; o < 256; o <<= 1) {
        int x = (t >= o) ? s[t - o] : 0;
        __syncthreads();
        s[t] += x;
        __syncthreads();
    }
    int run = s[t] - tsum;
    if (t == 255) bsums[blockIdx.x] = s[255];
#pragma unroll
    for (int j = 0; j < 4; ++j) {
        if (base + j < n) dst[base + j] = run;
        run += v[j];
    }
}

__global__ __launch_bounds__(256) void scan2(int* __restrict__ bsums, int nb) {
    __shared__ int s[256];
    const int t = threadIdx.x;
    int v = (t < nb) ? bsums[t] : 0;
    s[t] = v;
    __syncthreads();
    for (int o = 1; o < 256; o <<= 1) {
        int x = (t >= o) ? s[t - o] : 0;
        __syncthreads();
        s[t] += x;
        __syncthreads();
    }
    if (t < nb) bsums[t] = s[t] - v;
}

__global__ __launch_bounds__(256) void scan3(int* __restrict__ a,
                                             const int* __restrict__ bsums, int n) {
    int i = blockIdx.x * 256 + threadIdx.x;
    if (i < n) a[i] += bsums[i >> 10];
}

__global__ __launch_bounds__(256) void sort_scatter(const int* __restrict__ keys,
                                                    const int* __restrict__ vals,
                                                    const int* __restrict__ cscan,
                                                    int* __restrict__ bucketed,
                                                    int n, int B, int ipb) {
    __shared__ int cur[1024];
    const int tid = threadIdx.x;
    for (int i = tid; i < B; i += 256) cur[i] = cscan[i * NBLK + blockIdx.x];
    __syncthreads();
    const int start = blockIdx.x * ipb;
    const int end = (start + ipb < n) ? start + ipb : n;
    for (int i = start + tid; i < end; i += 256) {
        int k = keys[i];
        int p = atomicAdd(&cur[k >> SH], 1);
        bucketed[p] = (vals[i] << 8) | (k & 255);
    }
}

__global__ __launch_bounds__(256) void sort_finalize(const int* __restrict__ bucketed,
                                                     const int* __restrict__ cscan,
                                                     int* __restrict__ csr,
                                                     int* __restrict__ offs,
                                                     int* __restrict__ counts,
                                                     int n, int B, int nkeys) {
    __shared__ int s[256];
    __shared__ int cur[256];
    const int t = threadIdx.x;
    const int b = blockIdx.x;
    const int bstart = cscan[b * NBLK];
    const int bend = (b + 1 < B) ? cscan[(b + 1) * NBLK] : n;

    cur[t] = 0;
    __syncthreads();
    for (int i = bstart + t; i < bend; i += 256)
        atomicAdd(&cur[bucketed[i] & 255], 1);
    __syncthreads();
    const int cnt = cur[t];
    s[t] = cnt;
    __syncthreads();
    for (int o = 1; o < 256; o <<= 1) {
        int x = (t >= o) ? s[t - o] : 0;
        __syncthreads();
        s[t] += x;
        __syncthreads();
    }
    const int excl = s[t] - cnt;
    const int key = (b << SH) + t;
    if (key < nkeys) {
        offs[key] = bstart + excl;
        counts[key] = cnt;
    }
    __syncthreads();
    cur[t] = bstart + excl;
    __syncthreads();
    for (int i = bstart + t; i < bend; i += 256) {
        int e = bucketed[i];
        int p = atomicAdd(&cur[e & 255], 1);
        csr[p] = e >> 8;
    }
}

// ---------------------------------------------------------------------------
// Gather, fp16 src: wave per dest row; 4 rows in flight per iter group;
// 16 lanes/row * half4 (8B). Cross-group reduce via shfl_xor(16,32).
// ---------------------------------------------------------------------------
__global__ __launch_bounds__(256) void gather_h4(const _Float16* __restrict__ src,
                                                 const int* __restrict__ csr,
                                                 const int* __restrict__ offs,
                                                 const int* __restrict__ counts,
                                                 float* __restrict__ dst, int nrows) {
    const int wave = (blockIdx.x * 256 + threadIdx.x) >> 6;
    const int lane = threadIdx.x & 63;
    if (wave >= nrows) return;
    const int group = lane >> 4, sub = lane & 15;
    const int start = offs[wave];
    const int end = start + counts[wave];

    float ax = 0.f, ay = 0.f, az = 0.f, aw = 0.f;
    float bx = 0.f, by = 0.f, bz = 0.f, bw = 0.f;
    int j = start + group;
    for (; j + 4 < end; j += 8) {
        int s0 = csr[j];
        int s1 = csr[j + 4];
        half4v a = *(const half4v*)&src[((size_t)s0 << 6) + sub * 4];
        half4v b = *(const half4v*)&src[((size_t)s1 << 6) + sub * 4];
        ax += (float)a.x; ay += (float)a.y; az += (float)a.z; aw += (float)a.w;
        bx += (float)b.x; by += (float)b.y; bz += (float)b.z; bw += (float)b.w;
    }
    if (j < end) {
        half4v a = *(const half4v*)&src[((size_t)csr[j] << 6) + sub * 4];
        ax += (float)a.x; ay += (float)a.y; az += (float)a.z; aw += (float)a.w;
    }
    ax += bx; ay += by; az += bz; aw += bw;
#pragma unroll
    for (int o = 16; o <= 32; o <<= 1) {
        ax += __shfl_xor(ax, o);
        ay += __shfl_xor(ay, o);
        az += __shfl_xor(az, o);
        aw += __shfl_xor(aw, o);
    }
    if (group == 0)
        *(float4*)&dst[((size_t)wave << 6) + sub * 4] = make_float4(ax, ay, az, aw);
}

// Same structure, fp32 src (fallback when ws can't hold the half copy)
__global__ __launch_bounds__(256) void gather_f4(const float* __restrict__ src,
                                                 const int* __restrict__ csr,
                                                 const int* __restrict__ offs,
                                                 const int* __restrict__ counts,
                                                 float* __restrict__ dst, int nrows) {
    const int wave = (blockIdx.x * 256 + threadIdx.x) >> 6;
    const int lane = threadIdx.x & 63;
    if (wave >= nrows) return;
    const int group = lane >> 4, sub = lane & 15;
    const int start = offs[wave];
    const int end = start + counts[wave];

    float ax = 0.f, ay = 0.f, az = 0.f, aw = 0.f;
    float bx = 0.f, by = 0.f, bz = 0.f, bw = 0.f;
    int j = start + group;
    for (; j + 4 < end; j += 8) {
        int s0 = csr[j];
        int s1 = csr[j + 4];
        float4 a = *(const float4*)&src[((size_t)s0 << 6) + sub * 4];
        float4 b = *(const float4*)&src[((size_t)s1 << 6) + sub * 4];
        ax += a.x; ay += a.y; az += a.z; aw += a.w;
        bx += b.x; by += b.y; bz += b.z; bw += b.w;
    }
    if (j < end) {
        float4 a = *(const float4*)&src[((size_t)csr[j] << 6) + sub * 4];
        ax += a.x; ay += a.y; az += a.z; aw += a.w;
    }
    ax += bx; ay += by; az += bz; aw += bw;
#pragma unroll
    for (int o = 16; o <= 32; o <<= 1) {
        ax += __shfl_xor(ax, o);
        ay += __shfl_xor(ay, o);
        az += __shfl_xor(az, o);
        aw += __shfl_xor(aw, o);
    }
    if (group == 0)
        *(float4*)&dst[((size_t)wave << 6) + sub * 4] = make_float4(ax, ay, az, aw);
}

static void build_csr(const int* keys, const int* vals, int NI, int nkeys,
                      int* cmat, int* cscan, int* bsums, int* bucketed,
                      int* csr, int* offs, int* counts, hipStream_t stream) {
    const int B = (nkeys + 255) >> SH;
    const int L = B * NBLK;
    const int ipb = (NI + NBLK - 1) / NBLK;
    sort_hist<<<NBLK, 256, 0, stream>>>(keys, cmat, NI, B, ipb);
    scan1<<<(L + 1023) / 1024, 256, 0, stream>>>(cmat, cscan, bsums, L);
    scan2<<<1, 256, 0, stream>>>(bsums, (L + 1023) / 1024);
    scan3<<<(L + 255) / 256, 256, 0, stream>>>(cscan, bsums, L);
    sort_scatter<<<NBLK, 256, 0, stream>>>(keys, vals, cscan, bucketed, NI, B, ipb);
    sort_finalize<<<B, 256, 0, stream>>>(bucketed, cscan, csr, offs, counts, NI, B, nkeys);
}

extern "C" void kernel_launch(void* const* d_in, const int* in_sizes, int n_in,
                              void* d_out, int out_size, void* d_ws, size_t ws_size,
                              hipStream_t stream) {
    const float* node  = (const float*)d_in[0];
    const float* hedge = (const float*)d_in[1];
    const float* W_nn  = (const float*)d_in[2];
    const float* W_nh  = (const float*)d_in[3];
    const float* W_hh  = (const float*)d_in[4];
    const float* W_hn  = (const float*)d_in[5];
    const int* node_idx  = (const int*)d_in[6];
    const int* hedge_idx = (const int*)d_in[7];

    const int N  = in_sizes[0] / D;   // 200,000
    const int E  = in_sizes[1] / D;   // 100,000
    const int NI = in_sizes[6];       // 1,600,000
    const int maxNE = (N > E) ? N : E;
    const int maxB = (maxNE + 255) >> SH;

    float* out_node  = (float*)d_out;                  // [N,64]
    float* out_hedge = out_node + (size_t)N * D;       // [E,64]

    // ws: nbuf[N*D f32] | bucketed[NI] | csr[NI] | cmat | cscan | offs | counts |
    //     bsums[256] | nodeh[N*D f16] (optional)
    float*     nbuf     = (float*)d_ws;
    int*       bucketed = (int*)(nbuf + (size_t)N * D);
    int*       csr      = bucketed + NI;
    int*       cmat     = csr + NI;
    int*       cscan    = cmat + (size_t)maxB * NBLK;
    int*       offs     = cscan + (size_t)maxB * NBLK;
    int*       counts   = offs + maxNE;
    int*       bsums    = counts + maxNE;
    _Float16*  nodeh    = (_Float16*)(bsums + 256);

    const size_t need = (size_t)((char*)(nodeh + (size_t)N * D) - (char*)d_ws);
    const bool have_h = ws_size >= need;

    const int gbE = (E + 63) / 64;
    const int gbN = (N + 63) / 64;

    // ---------- phase 1: ngate = Mt-gather(hproj) ----------
    build_csr(node_idx, hedge_idx, NI, N, cmat, cscan, bsums, bucketed,
              csr, offs, counts, stream);
    // hproj = hedge @ W_nh, written fp16 into out_hedge scratch
    gemm64<0, 0, 1><<<gbE, 256, 0, stream>>>(hedge, W_nh, nullptr, nullptr,
                                             (_Float16*)out_hedge, E);
    gather_h4<<<(N + 3) / 4, 256, 0, stream>>>((const _Float16*)out_hedge, csr, offs,
                                               counts, nbuf, N);
    // new_node = tanh((node@W_nn)*ngate)  [+ fp16 copy if ws allows]
    if (have_h)
        gemm64<1, 1, 1><<<gbN, 256, 0, stream>>>(node, W_nn, nbuf, out_node, nodeh, N);
    else
        gemm64<1, 1, 0><<<gbN, 256, 0, stream>>>(node, W_nn, nbuf, out_node, nullptr, N);

    // ---------- phase 2: hgate = (M-gather(new_node)) @ W_hn ----------
    build_csr(hedge_idx, node_idx, NI, E, cmat, cscan, bsums, bucketed,
              csr, offs, counts, stream);
    if (have_h)
        gather_h4<<<(E + 3) / 4, 256, 0, stream>>>(nodeh, csr, offs, counts, nbuf, E);
    else
        gather_f4<<<(E + 3) / 4, 256, 0, stream>>>(out_node, csr, offs, counts, nbuf, E);
    // new_hedge = tanh((hedge@W_hh) * (agg@W_hn))
    gemm64_dual<<<gbE, 256, 0, stream>>>(hedge, W_hh, nbuf, W_hn, out_hedge, E);
}

// Round 7
// 471.298 us; speedup vs baseline: 4.2091x; 1.0690x over previous
//
#include <hip/hip_runtime.h>

#define D 64
#define SH 10             // bucket = key >> SH; 1024 keys/bucket
#define BK 1024
#define NBLK 256          // blocks for sort passes A1/A2

typedef _Float16 half4v __attribute__((ext_vector_type(4)));
typedef _Float16 half8 __attribute__((ext_vector_type(8)));
typedef float f32x4 __attribute__((ext_vector_type(4)));

__device__ __forceinline__ float fast_tanh(float x) {
    float e = __expf(2.f * x);
    return 1.f - 2.f * __builtin_amdgcn_rcpf(e + 1.f);
}

// ---------------------------------------------------------------------------
// Split-fp16 MFMA GEMM: C[M,64] = A[M,64] @ W[64,64], fp32-accurate via
// A=Ah+Ar, W=Wh+Wr (fp16 hi + fp16 residual); C ≈ AhWh + ArWh + AhWr.
// GATE: C = tanh(C * gate) (gate may alias Cf). WF: fp32 out. WH: fp16 out.
// Block: 64 rows, 4 waves; wave rt -> rows rt*16..+15. W staged transposed.
// ---------------------------------------------------------------------------
template <int GATE, int WF, int WH>
__global__ __launch_bounds__(256) void gemm64(const float* __restrict__ A,
                                              const float* __restrict__ W,
                                              const float* __restrict__ gate,
                                              float* __restrict__ Cf,
                                              _Float16* __restrict__ Ch, int M) {
    __shared__ _Float16 Ahi[64 * 72];
    __shared__ _Float16 Are[64 * 72];
    __shared__ _Float16 Whi[64 * 72];   // transposed: [n][k]
    __shared__ _Float16 Wre[64 * 72];
    const int tid = threadIdx.x;
    const int base = blockIdx.x * 64;

#pragma unroll
    for (int i = 0; i < 4; ++i) {
        int idx4 = (tid + i * 256) * 4;          // 0..4095 step 4
        int r = idx4 >> 6, k = idx4 & 63;
        float4 va = make_float4(0.f, 0.f, 0.f, 0.f);
        if (base + r < M) va = *(const float4*)&A[(size_t)(base + r) * D + k];
        half4v hh, hr;
        hh.x = (_Float16)va.x; hr.x = (_Float16)(va.x - (float)hh.x);
        hh.y = (_Float16)va.y; hr.y = (_Float16)(va.y - (float)hh.y);
        hh.z = (_Float16)va.z; hr.z = (_Float16)(va.z - (float)hh.z);
        hh.w = (_Float16)va.w; hr.w = (_Float16)(va.w - (float)hh.w);
        *(half4v*)&Ahi[r * 72 + k] = hh;
        *(half4v*)&Are[r * 72 + k] = hr;
        // W row-major [k][n] -> staged transposed [n][k]
        int wk = idx4 >> 6, wn = idx4 & 63;
        float4 vw = *(const float4*)&W[idx4];
#pragma unroll
        for (int j = 0; j < 4; ++j) {
            float w = (&vw.x)[j];
            _Float16 h = (_Float16)w;
            Whi[(wn + j) * 72 + wk] = h;
            Wre[(wn + j) * 72 + wk] = (_Float16)(w - (float)h);
        }
    }
    __syncthreads();

    const int lane = tid & 63;
    const int rt = tid >> 6;          // wave's 16-row tile
    const int m = lane & 15;          // A row in tile / C col in tile
    const int q = lane >> 4;          // k-subchunk

    f32x4 acc[4] = {};
#pragma unroll
    for (int kc = 0; kc < 64; kc += 32) {
        half8 ah = *(const half8*)&Ahi[(rt * 16 + m) * 72 + kc + q * 8];
        half8 ar = *(const half8*)&Are[(rt * 16 + m) * 72 + kc + q * 8];
#pragma unroll
        for (int ct = 0; ct < 4; ++ct) {
            half8 bh = *(const half8*)&Whi[(ct * 16 + m) * 72 + kc + q * 8];
            half8 br = *(const half8*)&Wre[(ct * 16 + m) * 72 + kc + q * 8];
            acc[ct] = __builtin_amdgcn_mfma_f32_16x16x32_f16(ah, bh, acc[ct], 0, 0, 0);
            acc[ct] = __builtin_amdgcn_mfma_f32_16x16x32_f16(ar, bh, acc[ct], 0, 0, 0);
            acc[ct] = __builtin_amdgcn_mfma_f32_16x16x32_f16(ah, br, acc[ct], 0, 0, 0);
        }
    }

#pragma unroll
    for (int r_ = 0; r_ < 4; ++r_) {
        int row = base + rt * 16 + q * 4 + r_;
        if (row < M) {
#pragma unroll
            for (int ct = 0; ct < 4; ++ct) {
                size_t off = (size_t)row * D + ct * 16 + m;
                float v = acc[ct][r_];
                if (GATE) v = fast_tanh(v * gate[off]);
                if (WF) Cf[off] = v;
                if (WH) Ch[off] = (_Float16)v;
            }
        }
    }
}

// --------------------- zero-global-atomic counting sort ---------------------
__global__ __launch_bounds__(256) void sort_hist(const int* __restrict__ keys,
                                                 int* __restrict__ cmat,
                                                 int n, int B, int ipb) {
    __shared__ int h[256];
    const int tid = threadIdx.x;
    for (int i = tid; i < B; i += 256) h[i] = 0;
    __syncthreads();
    const int start = blockIdx.x * ipb;
    const int end = (start + ipb < n) ? start + ipb : n;
    for (int i = start + tid; i < end; i += 256)
        atomicAdd(&h[keys[i] >> SH], 1);
    __syncthreads();
    for (int b = tid; b < B; b += 256) cmat[b * NBLK + blockIdx.x] = h[b];
}

__global__ __launch_bounds__(256) void scan1(const int* __restrict__ src,
                                             int* __restrict__ dst,
                                             int* __restrict__ bsums, int n) {
    __shared__ int s[256];
    const int t = threadIdx.x;
    const int base = blockIdx.x * 1024 + t * 4;
    int v[4];
#pragma unroll
    for (int j = 0; j < 4; ++j) v[j] = (base + j < n) ? src[base + j] : 0;
    int tsum = v[0] + v[1] + v[2] + v[3];
    s[t] = tsum;
    __syncthreads();
    for (int o = 1; o < 256; o <<= 1) {
        int x = (t >= o) ? s[t - o] : 0;
        __syncthreads();
        s[t] += x;
        __syncthreads();
    }
    int run = s[t] - tsum;
    if (t == 255) bsums[blockIdx.x] = s[255];
#pragma unroll
    for (int j = 0; j < 4; ++j) {
        if (base + j < n) dst[base + j] = run;
        run += v[j];
    }
}

__global__ __launch_bounds__(256) void scan2(int* __restrict__ bsums, int nb) {
    __shared__ int s[256];
    const int t = threadIdx.x;
    int v = (t < nb) ? bsums[t] : 0;
    s[t] = v;
    __syncthreads();
    for (int o = 1; o < 256; o <<= 1) {
        int x = (t >= o) ? s[t - o] : 0;
        __syncthreads();
        s[t] += x;
        __syncthreads();
    }
    if (t < nb) bsums[t] = s[t] - v;
}

__global__ __launch_bounds__(256) void scan3(int* __restrict__ a,
                                             const int* __restrict__ bsums, int n) {
    int i = blockIdx.x * 256 + threadIdx.x;
    if (i < n) a[i] += bsums[i >> 10];
}

__global__ __launch_bounds__(256) void sort_scatter(const int* __restrict__ keys,
                                                    const int* __restrict__ vals,
                                                    const int* __restrict__ cscan,
                                                    int* __restrict__ bucketed,
                                                    int n, int B, int ipb) {
    __shared__ int cur[256];
    const int tid = threadIdx.x;
    for (int i = tid; i < B; i += 256) cur[i] = cscan[i * NBLK + blockIdx.x];
    __syncthreads();
    const int start = blockIdx.x * ipb;
    const int end = (start + ipb < n) ? start + ipb : n;
    for (int i = start + tid; i < end; i += 256) {
        int k = keys[i];
        int p = atomicAdd(&cur[k >> SH], 1);
        bucketed[p] = (vals[i] << SH) | (k & (BK - 1));
    }
}

// Pass B: per-bucket exact CSR, 1024 keys/bucket
__global__ __launch_bounds__(256) void sort_finalize(const int* __restrict__ bucketed,
                                                     const int* __restrict__ cscan,
                                                     int* __restrict__ csr,
                                                     int* __restrict__ offs,
                                                     int* __restrict__ counts,
                                                     int n, int B, int nkeys) {
    __shared__ int h[BK];
    __shared__ int s[256];
    const int t = threadIdx.x;
    const int b = blockIdx.x;
    const int bstart = cscan[b * NBLK];
    const int bend = (b + 1 < B) ? cscan[(b + 1) * NBLK] : n;

    for (int i = t; i < BK; i += 256) h[i] = 0;
    __syncthreads();
    for (int i = bstart + t; i < bend; i += 256)
        atomicAdd(&h[bucketed[i] & (BK - 1)], 1);
    __syncthreads();
    const int c0 = h[t * 4], c1 = h[t * 4 + 1], c2 = h[t * 4 + 2], c3 = h[t * 4 + 3];
    const int tsum = c0 + c1 + c2 + c3;
    s[t] = tsum;
    __syncthreads();
    for (int o = 1; o < 256; o <<= 1) {
        int x = (t >= o) ? s[t - o] : 0;
        __syncthreads();
        s[t] += x;
        __syncthreads();
    }
    const int e0 = s[t] - tsum;
    const int e1 = e0 + c0, e2 = e1 + c1, e3 = e2 + c2;
    const int keyb = b * BK + t * 4;
    if (keyb + 0 < nkeys) { offs[keyb + 0] = bstart + e0; counts[keyb + 0] = c0; }
    if (keyb + 1 < nkeys) { offs[keyb + 1] = bstart + e1; counts[keyb + 1] = c1; }
    if (keyb + 2 < nkeys) { offs[keyb + 2] = bstart + e2; counts[keyb + 2] = c2; }
    if (keyb + 3 < nkeys) { offs[keyb + 3] = bstart + e3; counts[keyb + 3] = c3; }
    h[t * 4 + 0] = bstart + e0;
    h[t * 4 + 1] = bstart + e1;
    h[t * 4 + 2] = bstart + e2;
    h[t * 4 + 3] = bstart + e3;
    __syncthreads();
    for (int i = bstart + t; i < bend; i += 256) {
        int e = bucketed[i];
        int p = atomicAdd(&h[e & (BK - 1)], 1);
        csr[p] = e >> SH;
    }
}

// ---------------------------------------------------------------------------
// Gather fp16 src: wave/row, 4 row-fetches in flight, 16 lanes x half4.
// ---------------------------------------------------------------------------
__global__ __launch_bounds__(256) void gather_h4(const _Float16* __restrict__ src,
                                                 const int* __restrict__ csr,
                                                 const int* __restrict__ offs,
                                                 const int* __restrict__ counts,
                                                 float* __restrict__ dst, int nrows) {
    const int wave = (blockIdx.x * 256 + threadIdx.x) >> 6;
    const int lane = threadIdx.x & 63;
    if (wave >= nrows) return;
    const int group = lane >> 4, sub = lane & 15;
    const int start = offs[wave];
    const int end = start + counts[wave];

    float ax = 0.f, ay = 0.f, az = 0.f, aw = 0.f;
    float bx = 0.f, by = 0.f, bz = 0.f, bw = 0.f;
    int j = start + group;
    for (; j + 4 < end; j += 8) {
        int s0 = csr[j];
        int s1 = csr[j + 4];
        half4v a = *(const half4v*)&src[((size_t)s0 << 6) + sub * 4];
        half4v b = *(const half4v*)&src[((size_t)s1 << 6) + sub * 4];
        ax += (float)a.x; ay += (float)a.y; az += (float)a.z; aw += (float)a.w;
        bx += (float)b.x; by += (float)b.y; bz += (float)b.z; bw += (float)b.w;
    }
    if (j < end) {
        half4v a = *(const half4v*)&src[((size_t)csr[j] << 6) + sub * 4];
        ax += (float)a.x; ay += (float)a.y; az += (float)a.z; aw += (float)a.w;
    }
    ax += bx; ay += by; az += bz; aw += bw;
#pragma unroll
    for (int o = 16; o <= 32; o <<= 1) {
        ax += __shfl_xor(ax, o);
        ay += __shfl_xor(ay, o);
        az += __shfl_xor(az, o);
        aw += __shfl_xor(aw, o);
    }
    if (group == 0)
        *(float4*)&dst[((size_t)wave << 6) + sub * 4] = make_float4(ax, ay, az, aw);
}

__global__ __launch_bounds__(256) void gather_f4(const float* __restrict__ src,
                                                 const int* __restrict__ csr,
                                                 const int* __restrict__ offs,
                                                 const int* __restrict__ counts,
                                                 float* __restrict__ dst, int nrows) {
    const int wave = (blockIdx.x * 256 + threadIdx.x) >> 6;
    const int lane = threadIdx.x & 63;
    if (wave >= nrows) return;
    const int group = lane >> 4, sub = lane & 15;
    const int start = offs[wave];
    const int end = start + counts[wave];

    float ax = 0.f, ay = 0.f, az = 0.f, aw = 0.f;
    float bx = 0.f, by = 0.f, bz = 0.f, bw = 0.f;
    int j = start + group;
    for (; j + 4 < end; j += 8) {
        int s0 = csr[j];
        int s1 = csr[j + 4];
        float4 a = *(const float4*)&src[((size_t)s0 << 6) + sub * 4];
        float4 b = *(const float4*)&src[((size_t)s1 << 6) + sub * 4];
        ax += a.x; ay += a.y; az += a.z; aw += a.w;
        bx += b.x; by += b.y; bz += b.z; bw += b.w;
    }
    if (j < end) {
        float4 a = *(const float4*)&src[((size_t)csr[j] << 6) + sub * 4];
        ax += a.x; ay += a.y; az += a.z; aw += a.w;
    }
    ax += bx; ay += by; az += bz; aw += bw;
#pragma unroll
    for (int o = 16; o <= 32; o <<= 1) {
        ax += __shfl_xor(ax, o);
        ay += __shfl_xor(ay, o);
        az += __shfl_xor(az, o);
        aw += __shfl_xor(aw, o);
    }
    if (group == 0)
        *(float4*)&dst[((size_t)wave << 6) + sub * 4] = make_float4(ax, ay, az, aw);
}

static void build_csr(const int* keys, const int* vals, int NI, int nkeys,
                      int* cmat, int* cscan, int* bsums, int* bucketed,
                      int* csr, int* offs, int* counts, hipStream_t stream) {
    const int B = (nkeys + BK - 1) >> SH;
    const int L = B * NBLK;
    const int ipb = (NI + NBLK - 1) / NBLK;
    sort_hist<<<NBLK, 256, 0, stream>>>(keys, cmat, NI, B, ipb);
    scan1<<<(L + 1023) / 1024, 256, 0, stream>>>(cmat, cscan, bsums, L);
    scan2<<<1, 256, 0, stream>>>(bsums, (L + 1023) / 1024);
    scan3<<<(L + 255) / 256, 256, 0, stream>>>(cscan, bsums, L);
    sort_scatter<<<NBLK, 256, 0, stream>>>(keys, vals, cscan, bucketed, NI, B, ipb);
    sort_finalize<<<B, 256, 0, stream>>>(bucketed, cscan, csr, offs, counts, NI, B, nkeys);
}

extern "C" void kernel_launch(void* const* d_in, const int* in_sizes, int n_in,
                              void* d_out, int out_size, void* d_ws, size_t ws_size,
                              hipStream_t stream) {
    const float* node  = (const float*)d_in[0];
    const float* hedge = (const float*)d_in[1];
    const float* W_nn  = (const float*)d_in[2];
    const float* W_nh  = (const float*)d_in[3];
    const float* W_hh  = (const float*)d_in[4];
    const float* W_hn  = (const float*)d_in[5];
    const int* node_idx  = (const int*)d_in[6];
    const int* hedge_idx = (const int*)d_in[7];

    const int N  = in_sizes[0] / D;   // 200,000
    const int E  = in_sizes[1] / D;   // 100,000
    const int NI = in_sizes[6];       // 1,600,000
    const int maxNE = (N > E) ? N : E;
    const int maxB = (maxNE + BK - 1) >> SH;

    float* out_node  = (float*)d_out;                  // [N,64]
    float* out_hedge = out_node + (size_t)N * D;       // [E,64] (scratch: hproj fp16, g1 f32)

    float*     nbuf     = (float*)d_ws;                // ngate / agg (f32)
    int*       bucketed = (int*)(nbuf + (size_t)N * D);
    int*       csr      = bucketed + NI;
    int*       cmat     = csr + NI;
    int*       cscan    = cmat + (size_t)maxB * NBLK;
    int*       offs     = cscan + (size_t)maxB * NBLK;
    int*       counts   = offs + maxNE;
    int*       bsums    = counts + maxNE;
    _Float16*  nodeh    = (_Float16*)(bsums + 256);

    const size_t need = (size_t)((char*)(nodeh + (size_t)N * D) - (char*)d_ws);
    const bool have_h = ws_size >= need;

    const int gbE = (E + 63) / 64;
    const int gbN = (N + 63) / 64;

    // ---------- phase 1: ngate = Mt-gather(hproj) ----------
    build_csr(node_idx, hedge_idx, NI, N, cmat, cscan, bsums, bucketed,
              csr, offs, counts, stream);
    // hproj = hedge @ W_nh (fp16 into out_hedge scratch)
    gemm64<0, 0, 1><<<gbE, 256, 0, stream>>>(hedge, W_nh, nullptr, nullptr,
                                             (_Float16*)out_hedge, E);
    gather_h4<<<(N + 3) / 4, 256, 0, stream>>>((const _Float16*)out_hedge, csr, offs,
                                               counts, nbuf, N);
    // new_node = tanh((node@W_nn)*ngate)  [+ fp16 copy if ws allows]
    if (have_h)
        gemm64<1, 1, 1><<<gbN, 256, 0, stream>>>(node, W_nn, nbuf, out_node, nodeh, N);
    else
        gemm64<1, 1, 0><<<gbN, 256, 0, stream>>>(node, W_nn, nbuf, out_node, nullptr, N);

    // ---------- phase 2: new_hedge = tanh((hedge@W_hh) * ((Mt-gather new_node)@W_hn)) ----------
    build_csr(hedge_idx, node_idx, NI, E, cmat, cscan, bsums, bucketed,
              csr, offs, counts, stream);
    if (have_h)
        gather_h4<<<(E + 3) / 4, 256, 0, stream>>>(nodeh, csr, offs, counts, nbuf, E);
    else
        gather_f4<<<(E + 3) / 4, 256, 0, stream>>>(out_node, csr, offs, counts, nbuf, E);
    // g1 = hedge @ W_hh -> out_hedge (f32)
    gemm64<0, 1, 0><<<gbE, 256, 0, stream>>>(hedge, W_hh, nullptr, out_hedge, nullptr, E);
    // new_hedge = tanh((agg @ W_hn) * g1), in place over g1
    gemm64<1, 1, 0><<<gbE, 256, 0, stream>>>(nbuf, W_hn, out_hedge, out_hedge, nullptr, E);
}